// Round 13
// baseline (124.259 us; speedup 1.0000x reference)
//
#include <hip/hip_runtime.h>
#include <hip/hip_bf16.h>

// Problem: B=32, S=512, P=512, D=768
//   M = B*S = 16384 tokens, N = P = 512 prototypes, K = D = 768
// out[0 .. M*N)            = distances  ||x_m - p_n||^2  (fp32)
// out[M*N .. M*N + N*K)    = prototypes (fp32 passthrough)
//
// R18 = R10 (fragment-major B, best at 102.6us) + WAVE SPECIALIZATION.
//   12 rounds of evidence: vmcnt retires in order PER WAVE and __syncthreads
//   drains all counters, so intra-wave load-burst overlap is impossible
//   (R16 null) and phase-locked blocks convoy (R12 null). The escape the
//   guide documents (AITER pattern): producer waves' waits are INVISIBLE to
//   consumer waves. 768 thr = 12 waves:
//     waves 0-7  = consumers: R10's verified K-loop byte-for-byte (64
//                  protos/wave, acc[4][4], fragment-major coalesced B,
//                  depth-1 prefetch, same epilogue), but each k-step first
//                  spin-waits on a volatile LDS flag for its section.
//     waves 8-11 = producers: stream the 64x768 A-stripe in 24 K-sections
//                  of 32 (coalesced 128B row segments, fp32->bf16, x_sq
//                  partials), publish each via threadfence_block + flag.
//   NO __syncthreads between staging and compute: MFMA starts ~1.5us in
//   (after section 0); staging (~8us HBM) rides under the K-loop (6.2us
//   MFMA). Producers/consumers are same-block waves -> co-resident ->
//   deadlock-free. LDS 99.7KB (1 block/CU), lb(768,3) caps VGPR at 170.

#define M_TOK 16384
#define N_PROT 512
#define K_DIM 768
#define BK 32
#define NCH (K_DIM / BK)     // 24 sections == k-steps
#define ASTR (K_DIM + 8)     // 776: padded LDS row stride in bf16 units

typedef __attribute__((ext_vector_type(4))) float f32x4;
typedef __attribute__((ext_vector_type(8))) short bf16x8;

__device__ inline unsigned short f2bf(float f) {
    // round-to-nearest-even on the bit pattern (finite inputs)
    unsigned int u = __float_as_uint(f);
    u += 0x7fffu + ((u >> 16) & 1u);
    return (unsigned short)(u >> 16);
}

// One wave per prototype row: bf16 convert (fragment-major store) + ||p||^2
// + fp32 passthrough copy.  (unchanged from verified R10)
__global__ __launch_bounds__(256) void prep_b(
    const float* __restrict__ p,
    unsigned short* __restrict__ b_bf, float* __restrict__ p_sq,
    float* __restrict__ proto_out)
{
    const int row  = blockIdx.x * 4 + (threadIdx.x >> 6);
    const int lane = threadIdx.x & 63;

    const int g    = row >> 4;          // proto group 0..31
    const int l16p = row & 15;          // row within group

    const float4* src4 = (const float4*)(p + (size_t)row * K_DIM);
    float4* pout4 = (float4*)(proto_out + (size_t)row * K_DIM);

    float ssum = 0.0f;
#pragma unroll
    for (int j = 0; j < 3; ++j) {        // 192 float4 per row / 64 lanes
        const int idx = lane + j * 64;   // float4 index 0..191
        float4 v = src4[idx];
        ssum += v.x * v.x + v.y * v.y + v.z * v.z + v.w * v.w;
        ushort4 b;
        b.x = f2bf(v.x); b.y = f2bf(v.y); b.z = f2bf(v.z); b.w = f2bf(v.w);
        // fragment-major: element k -> block (g*24 + k>>5), slot
        // ((k>>3)&3)*16 + l16p (lane id), sub-offset k&7.
        const int k0   = idx * 4;               // first element of this ushort4
        const int kk   = k0 >> 5;               // k-step 0..23
        const int quad = (k0 >> 3) & 3;         // k-slice 0..3
        const int j0   = k0 & 7;                // 0 or 4
        const int dst  = (g * 24 + kk) * 512 + quad * 128 + l16p * 8 + j0;
        *(ushort4*)&b_bf[dst] = b;
        pout4[idx] = v;
    }
#pragma unroll
    for (int off = 32; off > 0; off >>= 1) ssum += __shfl_down(ssum, off);
    if (lane == 0) p_sq[row] = ssum;
}

__global__ __launch_bounds__(768, 3) void dist_main(
    const float* __restrict__ X,             // [M,K] fp32 tokens
    const unsigned short* __restrict__ Bb,   // fragment-major bf16 protos (ws)
    const float* __restrict__ p_sq,          // [N] fp32
    float* __restrict__ out)                 // [M,N] fp32 distances
{
    __shared__ unsigned short lds_a[64 * ASTR];   // 99,328 B full-K A stripe
    __shared__ float lds_xsq[64];
    __shared__ unsigned flags[NCH];               // section-ready flags

    const int tid  = threadIdx.x;
    const int wave = tid >> 6;           // 0..11
    const int lane = tid & 63;
    const int bm   = blockIdx.x << 6;    // 64-row A stripe

    if (tid < NCH) flags[tid] = 0u;
    if (tid < 64)  lds_xsq[tid] = 0.0f;
    __syncthreads();                     // barrier 1: flags/xsq initialized

    f32x4 acc[4][4];                     // consumer accumulators (live only there)

    if (wave < 8) {
        // ================= CONSUMER (R10's verified K-loop) =================
        const int quad = lane >> 4;      // 0..3
        const int l16  = lane & 15;

        // fragment-major B: block (g*24 + kk) of 1KB; lane's 16B at lane*16.
        const unsigned short* bp = Bb + (size_t)lane * 8;
        const int gbase = (wave << 2) * 24;      // (wave*4)*24

        const f32x4 zero = {0.0f, 0.0f, 0.0f, 0.0f};
#pragma unroll
        for (int mt = 0; mt < 4; ++mt)
#pragma unroll
            for (int nt = 0; nt < 4; ++nt) acc[mt][nt] = zero;

        bf16x8 bcur[4], bnxt[4];
#pragma unroll
        for (int nt = 0; nt < 4; ++nt)
            bcur[nt] = *(const bf16x8*)(bp + (size_t)(gbase + nt * 24) * 512);

        volatile unsigned* vf = flags;
        for (int kc = 0; kc < NCH; ++kc) {
            while (vf[kc] == 0u) { }     // broadcast LDS read; hot after warmup

            const int k0 = kc * BK;
            if (kc + 1 < NCH) {
#pragma unroll
                for (int nt = 0; nt < 4; ++nt)
                    bnxt[nt] = *(const bf16x8*)(bp
                        + (size_t)(gbase + nt * 24 + kc + 1) * 512);
            }

            bf16x8 af[4];
#pragma unroll
            for (int mt = 0; mt < 4; ++mt)
                af[mt] = *(const bf16x8*)&lds_a[(mt * 16 + l16) * ASTR + k0 + quad * 8];

#pragma unroll
            for (int mt = 0; mt < 4; ++mt)
#pragma unroll
                for (int nt = 0; nt < 4; ++nt)
                    acc[mt][nt] = __builtin_amdgcn_mfma_f32_16x16x32_bf16(
                        af[mt], bcur[nt], acc[mt][nt], 0, 0, 0);

#pragma unroll
            for (int nt = 0; nt < 4; ++nt) bcur[nt] = bnxt[nt];
        }
    } else {
        // ================= PRODUCER (4 waves stream A into LDS) =============
        const int pw = wave - 8;         // 0..3
        const int pr = lane >> 3;        // row sub-index 0..7
        const int pc = lane & 7;         // float4 col 0..7 within section
        // section kc covers k-float4s [kc*8, kc*8+8); rows handled in 8 iters
        // of 8 rows; lane reads row (i*8+pr), float4 (kc*8+pc): 8 lanes per
        // row = 128B contiguous per row-segment (coalesced).
        float asqp[8] = {0, 0, 0, 0, 0, 0, 0, 0};

        for (int s = 0; s < 6; ++s) {
            const int kc = pw + 4 * s;   // sections ready in order 0,1,2,3,...
            const float* base = X + (size_t)bm * K_DIM + (size_t)(kc * 8 + pc) * 4;
            float4 v[8];
#pragma unroll
            for (int i = 0; i < 8; ++i)
                v[i] = *(const float4*)(base + (size_t)(i * 8 + pr) * K_DIM);
#pragma unroll
            for (int i = 0; i < 8; ++i) {
                float4 x = v[i];
                asqp[i] += x.x * x.x + x.y * x.y + x.z * x.z + x.w * x.w;
                ushort4 u;
                u.x = f2bf(x.x); u.y = f2bf(x.y); u.z = f2bf(x.z); u.w = f2bf(x.w);
                *(ushort4*)&lds_a[(i * 8 + pr) * ASTR + (kc * 8 + pc) * 4] = u;
            }
            __threadfence_block();       // data in LDS before flag
            ((volatile unsigned*)flags)[kc] = 1u;
        }

        // x_sq: reduce each row's partial across the 8 lanes sharing it
#pragma unroll
        for (int i = 0; i < 8; ++i) {
            float t = asqp[i];
            t += __shfl_xor(t, 1);
            t += __shfl_xor(t, 2);
            t += __shfl_xor(t, 4);
            if (pc == 0) atomicAdd(&lds_xsq[i * 8 + pr], t);
        }
    }

    __syncthreads();                     // barrier 2: x_sq complete, all MFMA done

    // ================= EPILOGUE (consumers only; same as R10) ===============
    if (wave < 8) {
        const int quad = lane >> 4;
        const int l16  = lane & 15;
        const int wn   = wave << 6;

        float ps[4];
#pragma unroll
        for (int nt = 0; nt < 4; ++nt) ps[nt] = p_sq[wn + nt * 16 + l16];

#pragma unroll
        for (int mt = 0; mt < 4; ++mt) {
#pragma unroll
            for (int i = 0; i < 4; ++i) {
                const int lr = mt * 16 + quad * 4 + i;   // local row 0..63
                const float xs = lds_xsq[lr];
                float* orow = out + (size_t)(bm + lr) * N_PROT + wn + l16;
#pragma unroll
                for (int nt = 0; nt < 4; ++nt)
                    orow[nt * 16] = xs + ps[nt] - 2.0f * acc[mt][nt][i];
            }
        }
    }
}

extern "C" void kernel_launch(void* const* d_in, const int* in_sizes, int n_in,
                              void* d_out, int out_size, void* d_ws, size_t ws_size,
                              hipStream_t stream) {
    const float* inputs = (const float*)d_in[0];   // [32,512,768] fp32
    const float* protos = (const float*)d_in[1];   // [512,768]    fp32
    float* out = (float*)d_out;
    float* proto_out = out + (size_t)M_TOK * N_PROT;   // second tuple element

    // ws layout: b_bf 512*768*2 = 786,432 B (fragment-major) ; p_sq 2,048 B
    char* ws = (char*)d_ws;
    unsigned short* b_bf = (unsigned short*)ws;
    float* p_sq = (float*)(ws + 786432);

    prep_b<<<128, 256, 0, stream>>>(protos, b_bf, p_sq, proto_out);
    dist_main<<<M_TOK / 64, 768, 0, stream>>>(inputs, b_bf, p_sq, out);
}

// Round 14
// 116.727 us; speedup vs baseline: 1.0645x; 1.0645x over previous
//
#include <hip/hip_runtime.h>
#include <hip/hip_bf16.h>

// Problem: B=32, S=512, P=512, D=768
//   M = B*S = 16384 tokens, N = P = 512 prototypes, K = D = 768
// out[0 .. M*N)            = distances  ||x_m - p_n||^2  (fp32)
// out[M*N .. M*N + N*K)    = prototypes (fp32 passthrough)
//
// R19 = the one untried quadrant: CROSS-BLOCK overlap (2 blocks/CU) with
// clean fragment-major B and 64-row stripes.
//   Failed-attempt ledger: intra-wave bursts die on in-order vmcnt (R16
//   null); intra-block phases convoy on shared barriers (R12 null); wave
//   specialization starves staging + spin overhead (R18 -16us); rows<64
//   doubles B L2-traffic (R11); chunked staging kills burst ILP (R13).
//   Cross-block overlap needs NO compiler cooperation: separate blocks
//   have separate barriers and separate waitcnt state. R7 tried it but
//   carried two known-fatal defects (16-way scattered B-gather, fixed in
//   R10 for -13us; 2-load MLP-starved staging bursts, R13's killer).
//   Geometry: B-L2-traffic = M*N*K*2B/rows_block -> rows must stay 64
//   (201MB); cols don't matter -> N-split. Block = 64 tok x 256 protos,
//   LDS = two-section K staging in 64x392 shorts = 49KB -> 2 blocks/CU.
//   Per-wave tile = R12-verified 64x32 (acc[4][2]). Sections staged as
//   12-float4 full-ILP bursts. 3 barriers. XCD swizzle pairs a stripe's
//   two N-halves on one XCD (2nd A read L2-hot; A is L3-resident anyway).

#define M_TOK 16384
#define N_PROT 512
#define K_DIM 768
#define BK 32
#define NSK (K_DIM / BK)     // 24 k-steps total
#define KSEC 12              // k-steps per section (K=384)
#define ASTR2 392            // LDS row stride (bf16): 384 + 8 pad (4-bank skew)

typedef __attribute__((ext_vector_type(4))) float f32x4;
typedef __attribute__((ext_vector_type(8))) short bf16x8;

__device__ inline unsigned short f2bf(float f) {
    // round-to-nearest-even on the bit pattern (finite inputs)
    unsigned int u = __float_as_uint(f);
    u += 0x7fffu + ((u >> 16) & 1u);
    return (unsigned short)(u >> 16);
}

// One wave per prototype row: bf16 convert (fragment-major store) + ||p||^2
// + fp32 passthrough copy.  (unchanged from verified R10)
__global__ __launch_bounds__(256) void prep_b(
    const float* __restrict__ p,
    unsigned short* __restrict__ b_bf, float* __restrict__ p_sq,
    float* __restrict__ proto_out)
{
    const int row  = blockIdx.x * 4 + (threadIdx.x >> 6);
    const int lane = threadIdx.x & 63;

    const int g    = row >> 4;          // proto group 0..31
    const int l16p = row & 15;          // row within group

    const float4* src4 = (const float4*)(p + (size_t)row * K_DIM);
    float4* pout4 = (float4*)(proto_out + (size_t)row * K_DIM);

    float ssum = 0.0f;
#pragma unroll
    for (int j = 0; j < 3; ++j) {        // 192 float4 per row / 64 lanes
        const int idx = lane + j * 64;   // float4 index 0..191
        float4 v = src4[idx];
        ssum += v.x * v.x + v.y * v.y + v.z * v.z + v.w * v.w;
        ushort4 b;
        b.x = f2bf(v.x); b.y = f2bf(v.y); b.z = f2bf(v.z); b.w = f2bf(v.w);
        // fragment-major: element k -> block (g*24 + k>>5), slot
        // ((k>>3)&3)*16 + l16p (lane id), sub-offset k&7.
        const int k0   = idx * 4;               // first element of this ushort4
        const int kk   = k0 >> 5;               // k-step 0..23
        const int quad = (k0 >> 3) & 3;         // k-slice 0..3
        const int j0   = k0 & 7;                // 0 or 4
        const int dst  = (g * 24 + kk) * 512 + quad * 128 + l16p * 8 + j0;
        *(ushort4*)&b_bf[dst] = b;
        pout4[idx] = v;
    }
#pragma unroll
    for (int off = 32; off > 0; off >>= 1) ssum += __shfl_down(ssum, off);
    if (lane == 0) p_sq[row] = ssum;
}

__global__ __launch_bounds__(512, 4) void dist_main(
    const float* __restrict__ X,             // [M,K] fp32 tokens
    const unsigned short* __restrict__ Bb,   // fragment-major bf16 protos (ws)
    const float* __restrict__ p_sq,          // [N] fp32
    float* __restrict__ out)                 // [M,N] fp32 distances
{
    __shared__ unsigned short lds_a[64 * ASTR2];  // 50,176 B: one K-section
    __shared__ float lds_xsq[64];

    // ---- block mapping: XCD swizzle; a stripe's two N-halves adjacent ----
    const int bid     = blockIdx.x;                    // 0..511
    const int logical = (bid & 7) * 64 + (bid >> 3);   // bijective 0..511
    const int ms = logical >> 1;                       // M-stripe 0..255
    const int nh = logical & 1;                        // N half
    const int bm = ms << 6;

    const int tid  = threadIdx.x;
    const int wave = tid >> 6;           // 0..7
    const int lane = tid & 63;
    const int wn   = (nh << 8) + (wave << 5);   // wave's 32-proto slice
    const int quad = lane >> 4;          // 0..3
    const int l16  = lane & 15;

    // ---- staging mapping: section = 64 rows x 96 float4; 12/thread ----
    const int ar = tid >> 3;             // row 0..63
    const int ac = tid & 7;              // float4 col base 0..7
    const float* aptr = X + (size_t)(bm + ar) * K_DIM;

    float asq = 0.0f;

    // ---- fragment-major B streams for this block's proto range ----
    const unsigned short* bp = Bb + (size_t)lane * 8;
    const int gbase = ((nh << 4) + (wave << 1)) * 24;  // group*24

    const f32x4 zero = {0.0f, 0.0f, 0.0f, 0.0f};
    f32x4 acc[4][2];
#pragma unroll
    for (int mt = 0; mt < 4; ++mt) {
        acc[mt][0] = zero; acc[mt][1] = zero;
    }

    bf16x8 bcur[2], bnxt[2];

    // ==== two K-sections; LDS buffer reused (barrier-guarded) ====
#pragma unroll
    for (int sec = 0; sec < 2; ++sec) {
        // ---- stage this section as one full-ILP burst (12 loads) ----
#pragma unroll
        for (int j = 0; j < 12; ++j) {
            const int c4 = ac + 8 * j;               // 0..95 within section
            float4 v = *(const float4*)(aptr + (size_t)(sec * 96 + c4) * 4);
            asq += v.x * v.x + v.y * v.y + v.z * v.z + v.w * v.w;
            ushort4 u;
            u.x = f2bf(v.x); u.y = f2bf(v.y); u.z = f2bf(v.z); u.w = f2bf(v.w);
            *(ushort4*)&lds_a[ar * ASTR2 + c4 * 4] = u;
        }
        __syncthreads();                 // section staged & (sec=1) prior reads done

        // ---- B depth-1 rotation for this section's 12 k-steps ----
        const int kk0 = sec * KSEC;
#pragma unroll
        for (int nt = 0; nt < 2; ++nt)
            bcur[nt] = *(const bf16x8*)(bp + (size_t)(gbase + nt * 24 + kk0) * 512);

        for (int ks = 0; ks < KSEC; ++ks) {
            const int kk = kk0 + ks;
            if (kk + 1 < NSK) {
#pragma unroll
                for (int nt = 0; nt < 2; ++nt)
                    bnxt[nt] = *(const bf16x8*)(bp
                        + (size_t)(gbase + nt * 24 + kk + 1) * 512);
            }

            bf16x8 af[4];
#pragma unroll
            for (int mt = 0; mt < 4; ++mt)
                af[mt] = *(const bf16x8*)&lds_a[(mt * 16 + l16) * ASTR2
                                                + ks * BK + quad * 8];

#pragma unroll
            for (int mt = 0; mt < 4; ++mt) {
                acc[mt][0] = __builtin_amdgcn_mfma_f32_16x16x32_bf16(
                    af[mt], bcur[0], acc[mt][0], 0, 0, 0);
                acc[mt][1] = __builtin_amdgcn_mfma_f32_16x16x32_bf16(
                    af[mt], bcur[1], acc[mt][1], 0, 0, 0);
            }
            bcur[0] = bnxt[0]; bcur[1] = bnxt[1];
        }

        if (sec == 0) __syncthreads();   // all reads of section 0 done
    }

    // ---- x_sq: reduce over the 8 staging threads of each row ----
#pragma unroll
    for (int off = 1; off < 8; off <<= 1) asq += __shfl_xor(asq, off);
    if (ac == 0) lds_xsq[ar] = asq;
    __syncthreads();

    // ---- epilogue: C/D layout col = lane&15, row = quad*4 + i ----
    float ps[2];
#pragma unroll
    for (int nt = 0; nt < 2; ++nt) ps[nt] = p_sq[wn + nt * 16 + l16];

#pragma unroll
    for (int mt = 0; mt < 4; ++mt) {
#pragma unroll
        for (int i = 0; i < 4; ++i) {
            const int lr = mt * 16 + quad * 4 + i;   // local row 0..63
            const float xs = lds_xsq[lr];
            float* orow = out + (size_t)(bm + lr) * N_PROT + wn + l16;
#pragma unroll
            for (int nt = 0; nt < 2; ++nt)
                orow[nt * 16] = xs + ps[nt] - 2.0f * acc[mt][nt][i];
        }
    }
}

extern "C" void kernel_launch(void* const* d_in, const int* in_sizes, int n_in,
                              void* d_out, int out_size, void* d_ws, size_t ws_size,
                              hipStream_t stream) {
    const float* inputs = (const float*)d_in[0];   // [32,512,768] fp32
    const float* protos = (const float*)d_in[1];   // [512,768]    fp32
    float* out = (float*)d_out;
    float* proto_out = out + (size_t)M_TOK * N_PROT;   // second tuple element

    // ws layout: b_bf 512*768*2 = 786,432 B (fragment-major) ; p_sq 2,048 B
    char* ws = (char*)d_ws;
    unsigned short* b_bf = (unsigned short*)ws;
    float* p_sq = (float*)(ws + 786432);

    prep_b<<<128, 256, 0, stream>>>(protos, b_bf, p_sq, proto_out);
    // 256 M-stripes x 2 N-halves = 512 blocks, 2 blocks/CU
    dist_main<<<512, 512, 0, stream>>>(inputs, b_bf, p_sq, out);
}

// Round 15
// 102.540 us; speedup vs baseline: 1.2118x; 1.1384x over previous
//
#include <hip/hip_runtime.h>
#include <hip/hip_bf16.h>

// Problem: B=32, S=512, P=512, D=768
//   M = B*S = 16384 tokens, N = P = 512 prototypes, K = D = 768
// out[0 .. M*N)            = distances  ||x_m - p_n||^2  (fp32)
// out[M*N .. M*N + N*K)    = prototypes (fp32 passthrough)
//
// R20 = R12 (best measured: 102.59us; 16-wave monolithic, fragment-major
// coalesced B, grid 256 = 1 block/CU) + DEPTH-2 B PREFETCH.
//   Ledger: all nine overlap structures measured negative or null (intra-
//   wave bursts: in-order vmcnt, R16; intra-block chunking: barrier convoy
//   + ILP loss, R13/R14; wave specialization: producer starvation, R18;
//   cross-block: phase lockstep, R19). R12's serial phase structure stands.
//   The one clean micro-fix never tested without confounds: B-prefetch
//   depth. Per k-step a SIMD retires ~160cyc MFMA (4 waves x 8) vs
//   ~200-300cyc L2 latency on the B pair -> depth-1 marginally too
//   shallow. Depth-2 (bcur/bmid/bnxt) costs +8 VGPR (52->60), no layout
//   change, and respects in-order vmcnt (wait on B(kk) leaves B(kk+1),
//   B(kk+2) as NEWER outstanding loads -> counted wait, no drain).
//   R8 tried depth-2 but was confounded by the 16-way scattered B-gather
//   (removed in R10). Everything else byte-identical to R12.

#define M_TOK 16384
#define N_PROT 512
#define K_DIM 768
#define BK 32
#define NCH (K_DIM / BK)     // 24
#define ASTR (K_DIM + 8)     // 776: padded LDS row stride in bf16 units

typedef __attribute__((ext_vector_type(4))) float f32x4;
typedef __attribute__((ext_vector_type(8))) short bf16x8;

__device__ inline unsigned short f2bf(float f) {
    // round-to-nearest-even on the bit pattern (finite inputs)
    unsigned int u = __float_as_uint(f);
    u += 0x7fffu + ((u >> 16) & 1u);
    return (unsigned short)(u >> 16);
}

// One wave per prototype row: bf16 convert (fragment-major store) + ||p||^2
// + fp32 passthrough copy.  (unchanged from verified R10)
__global__ __launch_bounds__(256) void prep_b(
    const float* __restrict__ p,
    unsigned short* __restrict__ b_bf, float* __restrict__ p_sq,
    float* __restrict__ proto_out)
{
    const int row  = blockIdx.x * 4 + (threadIdx.x >> 6);
    const int lane = threadIdx.x & 63;

    const int g    = row >> 4;          // proto group 0..31
    const int l16p = row & 15;          // row within group

    const float4* src4 = (const float4*)(p + (size_t)row * K_DIM);
    float4* pout4 = (float4*)(proto_out + (size_t)row * K_DIM);

    float ssum = 0.0f;
#pragma unroll
    for (int j = 0; j < 3; ++j) {        // 192 float4 per row / 64 lanes
        const int idx = lane + j * 64;   // float4 index 0..191
        float4 v = src4[idx];
        ssum += v.x * v.x + v.y * v.y + v.z * v.z + v.w * v.w;
        ushort4 b;
        b.x = f2bf(v.x); b.y = f2bf(v.y); b.z = f2bf(v.z); b.w = f2bf(v.w);
        // fragment-major: element k -> block (g*24 + k>>5), slot
        // ((k>>3)&3)*16 + l16p (lane id), sub-offset k&7.
        const int k0   = idx * 4;               // first element of this ushort4
        const int kk   = k0 >> 5;               // k-step 0..23
        const int quad = (k0 >> 3) & 3;         // k-slice 0..3
        const int j0   = k0 & 7;                // 0 or 4
        const int dst  = (g * 24 + kk) * 512 + quad * 128 + l16p * 8 + j0;
        *(ushort4*)&b_bf[dst] = b;
        pout4[idx] = v;
    }
#pragma unroll
    for (int off = 32; off > 0; off >>= 1) ssum += __shfl_down(ssum, off);
    if (lane == 0) p_sq[row] = ssum;
}

__global__ __launch_bounds__(1024, 4) void dist_main(
    const float* __restrict__ X,             // [M,K] fp32 tokens
    const unsigned short* __restrict__ Bb,   // fragment-major bf16 protos (ws)
    const float* __restrict__ p_sq,          // [N] fp32
    float* __restrict__ out)                 // [M,N] fp32 distances
{
    __shared__ unsigned short lds_a[64 * ASTR];   // ~97 KB, full-K A stripe
    __shared__ float lds_xsq[64];

    const int tid  = threadIdx.x;
    const int wave = tid >> 6;           // 0..15
    const int lane = tid & 63;
    const int bm   = blockIdx.x << 6;    // 64-row A stripe
    const int wn   = wave << 5;          // this wave's 32-col slice of N
    const int quad = lane >> 4;          // 0..3
    const int l16  = lane & 15;

    // ---- one-time A staging: fp32 -> (x_sq, bf16 LDS), 1024 threads ----
    const int ar = tid >> 4;             // 0..63 row
    const int ac = tid & 15;             // float4 col base
    const float* aptr = X + (size_t)(bm + ar) * K_DIM;
    float asq = 0.0f;
#pragma unroll
    for (int j = 0; j < 12; ++j) {
        const int c4 = ac + 16 * j;      // float4 index 0..191
        float4 v = *(const float4*)(aptr + (size_t)c4 * 4);
        asq += v.x * v.x + v.y * v.y + v.z * v.z + v.w * v.w;
        ushort4 u;
        u.x = f2bf(v.x); u.y = f2bf(v.y); u.z = f2bf(v.z); u.w = f2bf(v.w);
        *(ushort4*)&lds_a[ar * ASTR + c4 * 4] = u;
    }
#pragma unroll
    for (int off = 1; off < 16; off <<= 1) asq += __shfl_xor(asq, off);
    if (ac == 0) lds_xsq[ar] = asq;

    __syncthreads();   // the ONLY barrier

    // ---- barrier-free K-loop ----
    const f32x4 zero = {0.0f, 0.0f, 0.0f, 0.0f};
    f32x4 acc[4][2];
#pragma unroll
    for (int mt = 0; mt < 4; ++mt)
#pragma unroll
        for (int nt = 0; nt < 2; ++nt) acc[mt][nt] = zero;

    // fragment-major B: block (g*24 + kk) of 1KB; lane's 16B at lane*16.
    // wave's proto groups: g = wave*2 + nt (nt = 0,1). DEPTH-2 rotation.
    const unsigned short* bp = Bb + (size_t)lane * 8;
    const int gbase = (wave << 1) * 24;          // (wave*2)*24

    bf16x8 bcur[2], bmid[2], bnxt[2];
#pragma unroll
    for (int nt = 0; nt < 2; ++nt) {
        bcur[nt] = *(const bf16x8*)(bp + (size_t)(gbase + nt * 24) * 512);
        bmid[nt] = *(const bf16x8*)(bp + (size_t)(gbase + nt * 24 + 1) * 512);
    }

    for (int kc = 0; kc < NCH; ++kc) {
        if (kc + 2 < NCH) {
#pragma unroll
            for (int nt = 0; nt < 2; ++nt)
                bnxt[nt] = *(const bf16x8*)(bp
                    + (size_t)(gbase + nt * 24 + kc + 2) * 512);
        }

        const int k0 = kc * BK;
        bf16x8 af[4];
#pragma unroll
        for (int mt = 0; mt < 4; ++mt)
            af[mt] = *(const bf16x8*)&lds_a[(mt * 16 + l16) * ASTR + k0 + quad * 8];

#pragma unroll
        for (int mt = 0; mt < 4; ++mt)
#pragma unroll
            for (int nt = 0; nt < 2; ++nt)
                acc[mt][nt] = __builtin_amdgcn_mfma_f32_16x16x32_bf16(
                    af[mt], bcur[nt], acc[mt][nt], 0, 0, 0);

#pragma unroll
        for (int nt = 0; nt < 2; ++nt) {
            bcur[nt] = bmid[nt];
            bmid[nt] = bnxt[nt];
        }
    }

    // ---- epilogue: C/D layout col = lane&15, row = quad*4 + i ----
    float ps[2];
#pragma unroll
    for (int nt = 0; nt < 2; ++nt) ps[nt] = p_sq[wn + nt * 16 + l16];

#pragma unroll
    for (int mt = 0; mt < 4; ++mt) {
#pragma unroll
        for (int i = 0; i < 4; ++i) {
            const int lr = mt * 16 + quad * 4 + i;   // local row 0..63
            const float xs = lds_xsq[lr];
            float* orow = out + (size_t)(bm + lr) * N_PROT + wn + l16;
#pragma unroll
            for (int nt = 0; nt < 2; ++nt)
                orow[nt * 16] = xs + ps[nt] - 2.0f * acc[mt][nt][i];
        }
    }
}

extern "C" void kernel_launch(void* const* d_in, const int* in_sizes, int n_in,
                              void* d_out, int out_size, void* d_ws, size_t ws_size,
                              hipStream_t stream) {
    const float* inputs = (const float*)d_in[0];   // [32,512,768] fp32
    const float* protos = (const float*)d_in[1];   // [512,768]    fp32
    float* out = (float*)d_out;
    float* proto_out = out + (size_t)M_TOK * N_PROT;   // second tuple element

    // ws layout: b_bf 512*768*2 = 786,432 B (fragment-major) ; p_sq 2,048 B
    char* ws = (char*)d_ws;
    unsigned short* b_bf = (unsigned short*)ws;
    float* p_sq = (float*)(ws + 786432);

    prep_b<<<128, 256, 0, stream>>>(protos, b_bf, p_sq, proto_out);
    dist_main<<<M_TOK / 64, 1024, 0, stream>>>(inputs, b_bf, p_sq, out);
}